// Round 1
// 1806.493 us; speedup vs baseline: 1.3351x; 1.3351x over previous
//
#include <hip/hip_runtime.h>
#include <math.h>
#include <stdint.h>

// Problem constants (per batch): C=64, H=W=256, P=65536 pixels.
#define P_ 65536

// ---- per-batch workspace layout (float offsets). Peak = 33,423,360 floats
// ---- = 127.5 MiB (identical to round-2/3/4 known-good footprint).
#define DW_OFF   0ul            // 192*P (q,k,v post-dwconv)
#define QKV_OFF  12582912ul     // 192*P (pre-dwconv)  [dead after dwconv]
#define ATTP_OFF QKV_OFF        // 64*P K-split partials ALIAS dead QKV region
#define Y_OFF    25165824ul     // 64*P  (attn out)
#define ATT_OFF  31457280ul     // P     (softmaxed attention)
// stage C overlays:
#define HID_OFF  0ul            // 340*P
#define G_OFF    22282240ul     // 170*P

typedef __attribute__((ext_vector_type(8))) short bf16x8;   // 8 bf16 in 4 VGPRs
typedef __attribute__((ext_vector_type(4))) float f32x4;

__device__ __forceinline__ unsigned short f2bf(float f) {   // RNE fp32->bf16
    uint32_t u = __float_as_uint(f);
    return (unsigned short)((u + 0x7FFFu + ((u >> 16) & 1u)) >> 16);
}
__device__ __forceinline__ float bf2f(unsigned short h) {
    return __uint_as_float((uint32_t)h << 16);
}

// ============== MFMA 1x1 conv: out[o,p] = sum_c W[o,c]*X[c,p] ===============
// 64-pixel tile per block, 256 threads = 4 waves. Wave w owns px-tile w (16
// px); loops over 4 o-tiles per 64-o chunk. LDS bf16 [px][c] / [o][c] with
// 16B k-blocks XOR-swizzled by (row&7) -> 2-way bank aliasing (free).
// A-frag: A[m=lane&15][k=quad*8+j]; B-frag: B[k=quad*8+j][n=lane&15];
// D: row=(quad*4+reg) (o), col=lane&15 (px). fp32 epilogue: +bias [+res].
template<int CIN, int CPAD, int COUT, bool LN, bool RES>
__global__ __launch_bounds__(256) void conv_mfma_kernel(
        const float* __restrict__ in, const float* __restrict__ lnw,
        const float* __restrict__ lnb, const float* __restrict__ Wt,
        const float* __restrict__ bias, float* __restrict__ out,
        const float* __restrict__ res) {
    constexpr int NSL = CPAD / 32;           // K slices of 32
    __shared__ unsigned short sX[64 * CPAD];
    __shared__ unsigned short sW[64 * CPAD];
    __shared__ float sPa[256], sPb[256], sMu[64], sInv[64];
    int tid = threadIdx.x;
    int hw0 = blockIdx.x * 64;
    int lane = tid & 63, wave = tid >> 6;

    {   // ---- stage X: fp32 global -> bf16 swizzled LDS [px][c] ----
        uint32_t* sX32 = (uint32_t*)sX;
        #pragma unroll
        for (int it = 0; it < CPAD / 8; ++it) {
            int idx = tid + it * 256;
            int p = idx & 63, c = (idx >> 6) * 2;
            float v0 = (c < CIN)     ? in[(size_t)c * P_ + hw0 + p]     : 0.f;
            float v1 = (c + 1 < CIN) ? in[(size_t)(c+1) * P_ + hw0 + p] : 0.f;
            uint32_t pk = (uint32_t)f2bf(v0) | ((uint32_t)f2bf(v1) << 16);
            int kb = c >> 3;
            sX32[(p * CPAD + (((kb ^ (p & 7)) << 3) | (c & 7))) >> 1] = pk;
        }
    }
    __syncthreads();
    if constexpr (LN) {                      // per-pixel LN over 64 channels
        int p = tid & 63, q = tid >> 6;
        float s = 0.f, s2 = 0.f;
        #pragma unroll
        for (int c = q * 16; c < q * 16 + 16; ++c) {
            float v = bf2f(sX[p * 64 + ((((c >> 3) ^ (p & 7)) << 3) | (c & 7))]);
            s += v; s2 += v * v;
        }
        sPa[tid] = s; sPb[tid] = s2;
        __syncthreads();
        if (tid < 64) {
            float ss = sPa[tid] + sPa[tid+64] + sPa[tid+128] + sPa[tid+192];
            float qq = sPb[tid] + sPb[tid+64] + sPb[tid+128] + sPb[tid+192];
            float mu = ss * (1.f/64.f);
            float var = qq * (1.f/64.f) - mu * mu;
            sMu[tid] = mu; sInv[tid] = rsqrtf(var + 1e-5f);
        }
        __syncthreads();
        float mu = sMu[p], inv = sInv[p];
        #pragma unroll
        for (int c = q * 16; c < q * 16 + 16; ++c) {
            int sw = p * 64 + ((((c >> 3) ^ (p & 7)) << 3) | (c & 7));
            float v = bf2f(sX[sw]);
            sX[sw] = f2bf((v - mu) * inv * lnw[c] + lnb[c]);
        }
        __syncthreads();
    }

    int pxl = lane & 15, quad = lane >> 4;
    int pgl = hw0 + wave * 16 + pxl;         // this lane's global pixel
    for (int o0 = 0; o0 < COUT; o0 += 64) {
        __syncthreads();                     // previous chunk's sW reads done
        {   // ---- stage weight chunk: [o][c] bf16 swizzled ----
            uint32_t* sW32 = (uint32_t*)sW;
            #pragma unroll
            for (int it = 0; it < CPAD / 8; ++it) {
                int idx = tid + it * 256;
                int c2 = idx % (CPAD / 2), o = idx / (CPAD / 2);
                int c = c2 * 2, og = o0 + o;
                float v0 = (og < COUT && c < CIN)     ? Wt[(size_t)og * CIN + c]     : 0.f;
                float v1 = (og < COUT && c + 1 < CIN) ? Wt[(size_t)og * CIN + c + 1] : 0.f;
                uint32_t pk = (uint32_t)f2bf(v0) | ((uint32_t)f2bf(v1) << 16);
                int kb = c >> 3;
                sW32[(o * CPAD + (((kb ^ (o & 7)) << 3) | (c & 7))) >> 1] = pk;
            }
        }
        __syncthreads();
        f32x4 acc[4];
        #pragma unroll
        for (int ot = 0; ot < 4; ++ot) acc[ot] = (f32x4){0.f, 0.f, 0.f, 0.f};
        #pragma unroll
        for (int s = 0; s < NSL; ++s) {
            int p = wave * 16 + pxl;
            int kb = s * 4 + quad;
            bf16x8 bfrag = *(const bf16x8*)&sX[p * CPAD + ((kb ^ (p & 7)) << 3)];
            #pragma unroll
            for (int ot = 0; ot < 4; ++ot) {
                int o = ot * 16 + pxl;
                bf16x8 afrag = *(const bf16x8*)&sW[o * CPAD + ((kb ^ (o & 7)) << 3)];
                acc[ot] = __builtin_amdgcn_mfma_f32_16x16x32_bf16(afrag, bfrag, acc[ot], 0, 0, 0);
            }
        }
        #pragma unroll
        for (int ot = 0; ot < 4; ++ot) {
            #pragma unroll
            for (int r = 0; r < 4; ++r) {
                int og = o0 + ot * 16 + quad * 4 + r;
                if (COUT % 64 == 0 || og < COUT) {
                    size_t ob = (size_t)og * P_ + pgl;
                    float v = acc[ot][r] + bias[og];
                    if constexpr (RES) v += res[ob];
                    out[ob] = v;
                }
            }
        }
    }
}

// ============ unified 128x128-tile fp32 GEMM core, 8x8 micro-tile ===========
#define GEMM_ACC_DECL float4 acc[8][2]; \
    _Pragma("unroll") for (int a_ = 0; a_ < 8; ++a_) { \
        acc[a_][0] = make_float4(0.f,0.f,0.f,0.f); \
        acc[a_][1] = make_float4(0.f,0.f,0.f,0.f); }

__device__ __forceinline__ void gemm_inner16(const float* As, const float* Bs,
        int tx, int ty, float4 acc[8][2]) {
    const float4* As4 = (const float4*)As;
    const float4* Bs4 = (const float4*)Bs;
    #pragma unroll
    for (int kk = 0; kk < 16; ++kk) {
        float4 a0 = As4[kk*33 + ty*2];
        float4 a1 = As4[kk*33 + ty*2 + 1];
        float4 b0 = Bs4[kk*33 + tx*2];
        float4 b1 = Bs4[kk*33 + tx*2 + 1];
        float av[8] = {a0.x,a0.y,a0.z,a0.w,a1.x,a1.y,a1.z,a1.w};
        #pragma unroll
        for (int a = 0; a < 8; ++a) {
            acc[a][0].x += av[a]*b0.x; acc[a][0].y += av[a]*b0.y;
            acc[a][0].z += av[a]*b0.z; acc[a][0].w += av[a]*b0.w;
            acc[a][1].x += av[a]*b1.x; acc[a][1].y += av[a]*b1.y;
            acc[a][1].z += av[a]*b1.z; acc[a][1].w += av[a]*b1.w;
        }
    }
}

// ---- attention logits: part[ks][i][j] over one channel ks ------------------
template<bool RCONTIG>
__global__ __launch_bounds__(256) void attn_gemm_kernel(const float* __restrict__ dw,
        float* __restrict__ part) {
    __shared__ float As[16*132], Bs[16*132];
    int tid = threadIdx.x, tx = tid & 15, ty = tid >> 4;
    int i0 = (blockIdx.x & 1) * 128, j0 = (blockIdx.x >> 1) * 128;
    int ks = blockIdx.y;
    const float* qc = dw + ((size_t)ks << 16);
    const float* kc = dw + ((size_t)(64 + ks) << 16);
    GEMM_ACC_DECL
    for (int r0 = 0; r0 < 256; r0 += 16) {
        __syncthreads();
        #pragma unroll
        for (int rep = 0; rep < 8; ++rep) {
            int idx = tid + rep * 256;
            if (RCONTIG) {
                int ii = idx >> 4, rr = idx & 15;
                As[rr*132 + ii] = qc[(i0+ii)*256 + r0+rr];
                Bs[rr*132 + ii] = kc[(j0+ii)*256 + r0+rr];
            } else {
                int rr = idx >> 7, ii = idx & 127;
                As[rr*132 + ii] = qc[(r0+rr)*256 + i0+ii];
                Bs[rr*132 + ii] = kc[(r0+rr)*256 + j0+ii];
            }
        }
        __syncthreads();
        gemm_inner16(As, Bs, tx, ty, acc);
    }
    float* pb = part + (size_t)ks * 65536;
    #pragma unroll
    for (int a = 0; a < 8; ++a) {
        float* row = pb + (size_t)(i0 + ty*8 + a) * 256 + j0 + tx*8;
        *(float4*)row = acc[a][0];
        *(float4*)(row + 4) = acc[a][1];
    }
}

// ---- av_w as GEMM: Out[(h,c), u] = sum_w V[c,h,w] * Att[w,u] ---------------
__global__ __launch_bounds__(256) void av_w_kernel(const float* __restrict__ dw,
        const float* __restrict__ att, float* __restrict__ out) {
    __shared__ float As[16*132], Bs[16*132];
    int tid = threadIdx.x, tx = tid & 15, ty = tid >> 4;
    int m0 = blockIdx.x * 128;
    int u0 = blockIdx.y * 128;
    GEMM_ACC_DECL
    for (int w0 = 0; w0 < 256; w0 += 16) {
        __syncthreads();
        #pragma unroll
        for (int rep = 0; rep < 8; ++rep) {
            int idx = tid + rep * 256;
            {   int mm = idx >> 4, wl = idx & 15;
                int m = m0 + mm, c = m & 63, h = m >> 6;
                As[wl*132 + mm] = dw[((size_t)(128+c) << 16) + h*256 + w0+wl];
            }
            {   int wl = idx >> 7, uu = idx & 127;
                Bs[wl*132 + uu] = att[(w0+wl)*256 + u0+uu];
            }
        }
        __syncthreads();
        gemm_inner16(As, Bs, tx, ty, acc);
    }
    #pragma unroll
    for (int a = 0; a < 8; ++a) {
        int m = m0 + ty*8 + a, c = m & 63, h = m >> 6;
        float* row = out + ((size_t)c << 16) + h*256 + u0 + tx*8;
        *(float4*)row = acc[a][0];
        *(float4*)(row + 4) = acc[a][1];
    }
}

// ---- av_h as GEMM: Out[(c,w), h] = sum_g V[c,g,w] * Att[h,g] ---------------
__global__ __launch_bounds__(256) void av_h_kernel(const float* __restrict__ dw,
        const float* __restrict__ att, float* __restrict__ out) {
    __shared__ float As[16*132], Bs[16*132];
    int tid = threadIdx.x, tx = tid & 15, ty = tid >> 4;
    int c = blockIdx.x >> 1;
    int w0 = (blockIdx.x & 1) * 128;
    int h0 = blockIdx.y * 128;
    const float* vc = dw + ((size_t)(128 + c) << 16);
    GEMM_ACC_DECL
    for (int g0 = 0; g0 < 256; g0 += 16) {
        __syncthreads();
        #pragma unroll
        for (int rep = 0; rep < 8; ++rep) {
            int idx = tid + rep * 256;
            {   int hh = idx >> 4, gl = idx & 15;
                As[gl*132 + hh] = att[(h0+hh)*256 + g0+gl];
            }
            {   int gl = idx >> 7, mm = idx & 127;
                Bs[gl*132 + mm] = vc[(g0+gl)*256 + w0+mm];
            }
        }
        __syncthreads();
        gemm_inner16(As, Bs, tx, ty, acc);
    }
    #pragma unroll
    for (int a = 0; a < 8; ++a) {
        int h = h0 + ty*8 + a;
        float* row = out + ((size_t)c << 16) + h*256 + w0 + tx*8;
        *(float4*)row = acc[a][0];
        *(float4*)(row + 4) = acc[a][1];
    }
}

// ---------------- sum 64 K-split partials, scale by temp, softmax row -------
__global__ __launch_bounds__(256) void softmax_kernel(const float* __restrict__ part,
        const float* __restrict__ temp, float* __restrict__ att) {
    int i = blockIdx.x;
    int j = threadIdx.x;
    size_t rowoff = (size_t)i * 256 + j;
    float s = 0.f;
    #pragma unroll
    for (int kk = 0; kk < 64; ++kk) s += part[(size_t)kk * 65536 + rowoff];
    s *= temp[0];
    __shared__ float redA[4], redB[4];
    int wv = j >> 6, ln = j & 63;
    float m = s;
    #pragma unroll
    for (int off = 32; off; off >>= 1) m = fmaxf(m, __shfl_down(m, off, 64));
    if (ln == 0) redA[wv] = m;
    __syncthreads();
    m = fmaxf(fmaxf(redA[0], redA[1]), fmaxf(redA[2], redA[3]));
    float e = expf(s - m);
    float t2 = e;
    #pragma unroll
    for (int off = 32; off; off >>= 1) t2 += __shfl_down(t2, off, 64);
    if (ln == 0) redB[wv] = t2;
    __syncthreads();
    float tot = redB[0] + redB[1] + redB[2] + redB[3];
    att[rowoff] = e / tot;
}

// ======= wave-per-row depthwise 3x3 + bias, optional L2-norm over w =========
// One wave handles one full (o,h) row: 64 lanes x 4 px (float4). Halo pixels
// come from neighbor lanes via __shfl; w-norm (q,k: o<128) is an in-wave
// __shfl_xor butterfly. No LDS, no __syncthreads. 4 waves (4 rows of same o)
// per 256-thread block.
template<bool NORM>
__global__ __launch_bounds__(256) void dw_row_kernel(const float* __restrict__ in,
        const float* __restrict__ w9, const float* __restrict__ bias,
        float* __restrict__ out) {
    int row = __builtin_amdgcn_readfirstlane(blockIdx.x * 4 + (threadIdx.x >> 6));
    int o = row >> 8, h = row & 255;
    int lane = threadIdx.x & 63;
    const float* ip = in + ((size_t)o << 16);
    const float* wp = w9 + o * 9;
    float b = bias[o];
    float4 acc = make_float4(b, b, b, b);
    #pragma unroll
    for (int dy = -1; dy <= 1; ++dy) {
        int hh = h + dy;
        float4 v = make_float4(0.f, 0.f, 0.f, 0.f);
        if (hh >= 0 && hh <= 255)
            v = *(const float4*)(ip + hh * 256 + lane * 4);
        float lft = __shfl(v.w, lane - 1);
        float rgt = __shfl(v.x, lane + 1);
        if (lane == 0)  lft = 0.f;
        if (lane == 63) rgt = 0.f;
        float w0 = wp[(dy+1)*3], w1 = wp[(dy+1)*3+1], w2 = wp[(dy+1)*3+2];
        acc.x += w0*lft + w1*v.x + w2*v.y;
        acc.y += w0*v.x + w1*v.y + w2*v.z;
        acc.z += w0*v.y + w1*v.z + w2*v.w;
        acc.w += w0*v.z + w1*v.w + w2*rgt;
    }
    if constexpr (NORM) {
        if (o < 128) {   // q,k channels: l2-normalize this w-row
            float s = acc.x*acc.x + acc.y*acc.y + acc.z*acc.z + acc.w*acc.w;
            #pragma unroll
            for (int off = 32; off; off >>= 1) s += __shfl_xor(s, off, 64);
            float inv = 1.0f / fmaxf(sqrtf(s), 1e-12f);
            acc.x *= inv; acc.y *= inv; acc.z *= inv; acc.w *= inv;
        }
    }
    *(float4*)(out + ((size_t)o << 16) + h * 256 + lane * 4) = acc;
}

// ===== wave-per-row FFN depthwise 3x3 pair fused with exact-GELU gate =======
__global__ __launch_bounds__(256) void ffn_dw_row_kernel(const float* __restrict__ hid,
        const float* __restrict__ w9, const float* __restrict__ bias,
        float* __restrict__ g) {
    int row = __builtin_amdgcn_readfirstlane(blockIdx.x * 4 + (threadIdx.x >> 6));
    int i = row >> 8, h = row & 255;
    int lane = threadIdx.x & 63;
    const float* ip1 = hid + ((size_t)i << 16);
    const float* ip2 = ip1 + ((size_t)170 << 16);
    const float* wp1 = w9 + i * 9;
    const float* wp2 = w9 + (i + 170) * 9;
    float ba = bias[i], bb = bias[i + 170];
    float4 a = make_float4(ba, ba, ba, ba);
    float4 c = make_float4(bb, bb, bb, bb);
    #pragma unroll
    for (int dy = -1; dy <= 1; ++dy) {
        int hh = h + dy;
        float4 v1 = make_float4(0.f, 0.f, 0.f, 0.f);
        float4 v2 = make_float4(0.f, 0.f, 0.f, 0.f);
        if (hh >= 0 && hh <= 255) {
            v1 = *(const float4*)(ip1 + hh * 256 + lane * 4);
            v2 = *(const float4*)(ip2 + hh * 256 + lane * 4);
        }
        float l1 = __shfl(v1.w, lane - 1), r1 = __shfl(v1.x, lane + 1);
        float l2 = __shfl(v2.w, lane - 1), r2 = __shfl(v2.x, lane + 1);
        if (lane == 0)  { l1 = 0.f; l2 = 0.f; }
        if (lane == 63) { r1 = 0.f; r2 = 0.f; }
        float u0 = wp1[(dy+1)*3], u1 = wp1[(dy+1)*3+1], u2 = wp1[(dy+1)*3+2];
        float q0 = wp2[(dy+1)*3], q1 = wp2[(dy+1)*3+1], q2 = wp2[(dy+1)*3+2];
        a.x += u0*l1   + u1*v1.x + u2*v1.y;
        a.y += u0*v1.x + u1*v1.y + u2*v1.z;
        a.z += u0*v1.y + u1*v1.z + u2*v1.w;
        a.w += u0*v1.z + u1*v1.w + u2*r1;
        c.x += q0*l2   + q1*v2.x + q2*v2.y;
        c.y += q0*v2.x + q1*v2.y + q2*v2.z;
        c.z += q0*v2.y + q1*v2.z + q2*v2.w;
        c.w += q0*v2.z + q1*v2.w + q2*r2;
    }
    const float ISQ2 = 0.70710678118654752440f;
    float4 r;
    r.x = 0.5f * a.x * (1.0f + erff(a.x * ISQ2)) * c.x;
    r.y = 0.5f * a.y * (1.0f + erff(a.y * ISQ2)) * c.y;
    r.z = 0.5f * a.z * (1.0f + erff(a.z * ISQ2)) * c.z;
    r.w = 0.5f * a.w * (1.0f + erff(a.w * ISQ2)) * c.w;
    *(float4*)(g + ((size_t)i << 16) + h * 256 + lane * 4) = r;
}

// ---------------- l2 normalize over (c,w), per (q|k, h) ---------------------
__global__ __launch_bounds__(256) void l2norm_h_kernel(float* __restrict__ dw) {
    int h = blockIdx.x, qk = blockIdx.y;
    float* base = dw + ((size_t)(qk*64) << 16) + h*256;
    int tid = threadIdx.x;
    float s = 0.f;
    for (int idx = tid; idx < 16384; idx += 256) {
        int c = idx >> 8, w = idx & 255;
        float v = base[((size_t)c << 16) + w];
        s += v * v;
    }
    #pragma unroll
    for (int off = 32; off; off >>= 1) s += __shfl_down(s, off, 64);
    __shared__ float red[4];
    int wv = tid >> 6, ln = tid & 63;
    if (ln == 0) red[wv] = s;
    __syncthreads();
    float tot = red[0] + red[1] + red[2] + red[3];
    float inv = 1.0f / fmaxf(sqrtf(tot), 1e-12f);
    for (int idx = tid; idx < 16384; idx += 256) {
        int c = idx >> 8, w = idx & 255;
        base[((size_t)c << 16) + w] *= inv;
    }
}

// ---------------------------------------------------------------------------
extern "C" void kernel_launch(void* const* d_in, const int* in_sizes, int n_in,
                              void* d_out, int out_size, void* d_ws, size_t ws_size,
                              hipStream_t stream) {
    (void)in_sizes; (void)n_in; (void)out_size; (void)ws_size;
    const float* x = (const float*)d_in[0];
    float* ws  = (float*)d_ws;
    float* out = (float*)d_out;
    float* DW   = ws + DW_OFF;
    float* QKV  = ws + QKV_OFF;
    float* ATTP = ws + ATTP_OFF;   // aliases QKV (dead by the time it's used)
    float* Y    = ws + Y_OFF;
    float* ATT  = ws + ATT_OFF;
    float* HID  = ws + HID_OFF;
    float* G    = ws + G_OFF;

    for (int b = 0; b < 4; ++b) {
        const float* xb = x + (size_t)b * 64 * P_;
        float* outb = out + (size_t)b * 64 * P_;

        // ===== stage A: attention over W (wxw); m -> d_out =====
        conv_mfma_kernel<64,64,192,true,false><<<1024, 256, 0, stream>>>(xb,
                (const float*)d_in[2], (const float*)d_in[3],
                (const float*)d_in[4], (const float*)d_in[5], QKV, nullptr);
        dw_row_kernel<true><<<12288, 256, 0, stream>>>(QKV,
                (const float*)d_in[6], (const float*)d_in[7], DW);
        attn_gemm_kernel<false><<<dim3(4,64), 256, 0, stream>>>(DW, ATTP);
        softmax_kernel<<<256, 256, 0, stream>>>(ATTP, (const float*)d_in[10], ATT);
        av_w_kernel<<<dim3(128,2), 256, 0, stream>>>(DW, ATT, Y);
        conv_mfma_kernel<64,64,64,false,true><<<1024, 256, 0, stream>>>(Y,
                nullptr, nullptr,
                (const float*)d_in[8], (const float*)d_in[9], outb, xb);

        // ===== stage B: attention over H (hxh); z -> d_out =====
        conv_mfma_kernel<64,64,192,true,false><<<1024, 256, 0, stream>>>(outb,
                (const float*)d_in[11], (const float*)d_in[12],
                (const float*)d_in[13], (const float*)d_in[14], QKV, nullptr);
        dw_row_kernel<false><<<12288, 256, 0, stream>>>(QKV,
                (const float*)d_in[15], (const float*)d_in[16], DW);
        l2norm_h_kernel<<<dim3(256,2), 256, 0, stream>>>(DW);
        attn_gemm_kernel<true><<<dim3(4,64), 256, 0, stream>>>(DW, ATTP);
        softmax_kernel<<<256, 256, 0, stream>>>(ATTP, (const float*)d_in[19], ATT);
        av_h_kernel<<<dim3(128,2), 256, 0, stream>>>(DW, ATT, Y);
        conv_mfma_kernel<64,64,64,false,true><<<1024, 256, 0, stream>>>(Y,
                nullptr, nullptr,
                (const float*)d_in[17], (const float*)d_in[18], outb, outb);

        // ===== stage C: gated FFN; z + ffn -> d_out =====
        conv_mfma_kernel<64,64,340,true,false><<<1024, 256, 0, stream>>>(outb,
                (const float*)d_in[20], (const float*)d_in[21],
                (const float*)d_in[22], (const float*)d_in[23], HID, nullptr);
        ffn_dw_row_kernel<<<10880, 256, 0, stream>>>(HID, (const float*)d_in[24],
                (const float*)d_in[25], G);
        conv_mfma_kernel<170,192,64,false,true><<<1024, 256, 0, stream>>>(G,
                nullptr, nullptr,
                (const float*)d_in[26], (const float*)d_in[27], outb, outb);
    }
}